// Round 1
// baseline (331.096 us; speedup 1.0000x reference)
//
#include <hip/hip_runtime.h>

using u16 = unsigned short;
using u32 = unsigned int;

typedef __attribute__((ext_vector_type(8))) short s16x8;
typedef __attribute__((ext_vector_type(8))) __bf16 bf16x8;
typedef __attribute__((ext_vector_type(4))) float f32x4;

static __device__ __forceinline__ u16 f2bf(float f) {
  u32 u = __builtin_bit_cast(u32, f);
  u32 r = u + 0x7FFFu + ((u >> 16) & 1u);
  return (u16)(r >> 16);
}

static __device__ __forceinline__ f32x4 mfma16(s16x8 a, s16x8 b, f32x4 c) {
  return __builtin_amdgcn_mfma_f32_16x16x32_bf16(
      __builtin_bit_cast(bf16x8, a), __builtin_bit_cast(bf16x8, b), c, 0, 0, 0);
}

#define GLOAD_LDS16(gp, lp)                                                    \
  __builtin_amdgcn_global_load_lds(                                            \
      (const __attribute__((address_space(1))) void*)(gp),                     \
      (__attribute__((address_space(3))) void*)(lp), 16, 0, 0)

// ---------------- f32 -> bf16 convert (vectorized) ----------------
__global__ __launch_bounds__(256) void k_cvt(const float* __restrict__ in,
                                             u16* __restrict__ out, int n) {
  int i = (blockIdx.x * 256 + threadIdx.x) * 8;
  if (i >= n) return;
  const float4 v0 = *(const float4*)(in + i);
  const float4 v1 = *(const float4*)(in + i + 4);
  s16x8 o;
  o[0] = f2bf(v0.x); o[1] = f2bf(v0.y); o[2] = f2bf(v0.z); o[3] = f2bf(v0.w);
  o[4] = f2bf(v1.x); o[5] = f2bf(v1.y); o[6] = f2bf(v1.z); o[7] = f2bf(v1.w);
  *(s16x8*)(out + i) = o;
}

// ------------- transpose + convert: src[K][N] f32 -> dst[N][K] bf16 -------------
__global__ __launch_bounds__(256) void k_transpose_cvt(const float* __restrict__ src,
                                                       u16* __restrict__ dst,
                                                       int K, int N) {
  __shared__ float tile[64][65];
  const int n0 = blockIdx.x * 64, k0 = blockIdx.y * 64;
  const int c = threadIdx.x & 63, r4 = threadIdx.x >> 6;
#pragma unroll
  for (int i = 0; i < 16; ++i) {
    int r = (i << 2) + r4;
    tile[r][c] = src[(k0 + r) * N + n0 + c];
  }
  __syncthreads();
#pragma unroll
  for (int i = 0; i < 16; ++i) {
    int r = (i << 2) + r4;
    dst[(n0 + r) * K + k0 + c] = f2bf(tile[c][r]);
  }
}

// ---------------- GEMM: C[M,N] = A[M,K] (bf16) @ BT[N,K]^T (bf16) ----------------
// MODE 0: epilogue scatters qkv -> q[BH][T][64] (scaled 1/8), k[BH][T][64], vT[BH][64][T]
// MODE 1: epilogue stores f32 to cout[M][N]
template <int MODE>
__global__ __launch_bounds__(256) void k_gemm(
    const u16* __restrict__ A, const u16* __restrict__ BT,
    u16* __restrict__ qg, u16* __restrict__ kg, u16* __restrict__ vtg,
    float* __restrict__ cout, int M, int N, int K) {
  __shared__ __align__(16) u16 As[128 * 32];
  __shared__ __align__(16) u16 Bs[128 * 32];
  const int t = threadIdx.x;
  const int lane = t & 63;
  const int w = t >> 6, wr = w >> 1, wc = w & 1;
  const int lrow = lane & 15, lkg = lane >> 4;
  const int m0 = blockIdx.y * 128, n0 = blockIdx.x * 128;

  const int ch1 = t + 256;
  const int ra0 = t >> 2, ca0 = (t & 3) << 3;
  const int ra1 = ch1 >> 2, ca1 = (ch1 & 3) << 3;
  const u16* gA0 = A + (m0 + ra0) * K + ca0;
  const u16* gA1 = A + (m0 + ra1) * K + ca1;
  const u16* gB0 = BT + (n0 + ra0) * K + ca0;
  const u16* gB1 = BT + (n0 + ra1) * K + ca1;
  u16* lA0 = &As[t * 8];
  u16* lA1 = &As[ch1 * 8];
  u16* lB0 = &Bs[t * 8];
  u16* lB1 = &Bs[ch1 * 8];

  f32x4 acc[4][4];
#pragma unroll
  for (int m = 0; m < 4; ++m)
#pragma unroll
    for (int n = 0; n < 4; ++n) acc[m][n] = (f32x4){0.f, 0.f, 0.f, 0.f};

  for (int k0 = 0; k0 < K; k0 += 32) {
    GLOAD_LDS16(gA0 + k0, lA0);
    GLOAD_LDS16(gA1 + k0, lA1);
    GLOAD_LDS16(gB0 + k0, lB0);
    GLOAD_LDS16(gB1 + k0, lB1);
    __syncthreads();
    s16x8 af[4], bfr[4];
#pragma unroll
    for (int m = 0; m < 4; ++m)
      af[m] = *(const s16x8*)&As[(wr * 64 + m * 16 + lrow) * 32 + lkg * 8];
#pragma unroll
    for (int n = 0; n < 4; ++n)
      bfr[n] = *(const s16x8*)&Bs[(wc * 64 + n * 16 + lrow) * 32 + lkg * 8];
#pragma unroll
    for (int m = 0; m < 4; ++m)
#pragma unroll
      for (int n = 0; n < 4; ++n) acc[m][n] = mfma16(af[m], bfr[n], acc[m][n]);
    __syncthreads();
  }

#pragma unroll
  for (int m = 0; m < 4; ++m)
#pragma unroll
    for (int n = 0; n < 4; ++n)
#pragma unroll
      for (int r = 0; r < 4; ++r) {
        const int rg = m0 + wr * 64 + m * 16 + lkg * 4 + r;
        const int cg = n0 + wc * 64 + n * 16 + lrow;
        const float v = acc[m][n][r];
        if (MODE == 0) {
          const int part = cg >> 10, rem = cg & 1023;
          const int h = rem >> 6, d = rem & 63;
          const int b = rg >> 11, tt = rg & 2047;
          const int bh = b * 16 + h;
          if (part == 0)
            qg[(bh * 2048 + tt) * 64 + d] = f2bf(v * 0.125f);
          else if (part == 1)
            kg[(bh * 2048 + tt) * 64 + d] = f2bf(v);
          else
            vtg[(bh * 64 + d) * 2048 + tt] = f2bf(v);
        } else {
          cout[rg * N + cg] = v;
        }
      }
}

// ---------------- causal flash attention ----------------
// 1 wave / block; 32 q-rows per block; KV chunks of 32; D = 64.
__global__ __launch_bounds__(64) void k_attn(const u16* __restrict__ qg,
                                             const u16* __restrict__ kg,
                                             const u16* __restrict__ vtg,
                                             u16* __restrict__ yb) {
  __shared__ __align__(16) u16 p_lds[32 * 40];
  const int lane = threadIdx.x;
  const int lrow = lane & 15, lkg = lane >> 4;
  const int qb = blockIdx.x, bh = blockIdx.y;
  const int q0 = qb * 32;
  const int hb = bh & 15, bb = bh >> 4;
  const f32x4 z4 = {0.f, 0.f, 0.f, 0.f};

  s16x8 aq[2][2];
#pragma unroll
  for (int m = 0; m < 2; ++m)
#pragma unroll
    for (int kk = 0; kk < 2; ++kk)
      aq[m][kk] = *(const s16x8*)&qg[((bh << 11) + q0 + m * 16 + lrow) * 64 +
                                     kk * 32 + lkg * 8];

  f32x4 o[2][4];
  float mst[2][4], lst[2][4];
#pragma unroll
  for (int m = 0; m < 2; ++m) {
#pragma unroll
    for (int c = 0; c < 4; ++c) o[m][c] = z4;
#pragma unroll
    for (int r = 0; r < 4; ++r) { mst[m][r] = -3e38f; lst[m][r] = 0.f; }
  }

  for (int kv0 = 0; kv0 <= q0; kv0 += 32) {
    // ---- S = Q K^T (pre-scaled Q) ----
    s16x8 bk[2][2];
#pragma unroll
    for (int c = 0; c < 2; ++c)
#pragma unroll
      for (int kk = 0; kk < 2; ++kk)
        bk[c][kk] = *(const s16x8*)&kg[((bh << 11) + kv0 + c * 16 + lrow) * 64 +
                                       kk * 32 + lkg * 8];
    f32x4 s[2][2];
#pragma unroll
    for (int m = 0; m < 2; ++m)
#pragma unroll
      for (int c = 0; c < 2; ++c)
        s[m][c] = mfma16(aq[m][1], bk[c][1], mfma16(aq[m][0], bk[c][0], z4));

    if (kv0 == q0) {  // diagonal tile: causal mask (relative offsets equal)
#pragma unroll
      for (int m = 0; m < 2; ++m) {
        const int rowg = m * 16 + lkg * 4;
#pragma unroll
        for (int c = 0; c < 2; ++c) {
          const int colg = c * 16 + lrow;
#pragma unroll
          for (int r = 0; r < 4; ++r)
            if (colg > rowg + r) s[m][c][r] = -3e38f;
        }
      }
    }

    // ---- online softmax (rows live in 16-lane groups) ----
    float pmax[2][4], al[2][4], ps[2][4];
#pragma unroll
    for (int m = 0; m < 2; ++m)
#pragma unroll
      for (int r = 0; r < 4; ++r) pmax[m][r] = fmaxf(s[m][0][r], s[m][1][r]);
#pragma unroll
    for (int d = 1; d < 16; d <<= 1)
#pragma unroll
      for (int m = 0; m < 2; ++m)
#pragma unroll
        for (int r = 0; r < 4; ++r)
          pmax[m][r] = fmaxf(pmax[m][r], __shfl_xor(pmax[m][r], d));
#pragma unroll
    for (int m = 0; m < 2; ++m)
#pragma unroll
      for (int r = 0; r < 4; ++r) {
        const float mn = fmaxf(mst[m][r], pmax[m][r]);
        al[m][r] = __expf(mst[m][r] - mn);
        mst[m][r] = mn;
      }
#pragma unroll
    for (int m = 0; m < 2; ++m)
#pragma unroll
      for (int c = 0; c < 2; ++c)
#pragma unroll
        for (int r = 0; r < 4; ++r) s[m][c][r] = __expf(s[m][c][r] - mst[m][r]);
#pragma unroll
    for (int m = 0; m < 2; ++m)
#pragma unroll
      for (int r = 0; r < 4; ++r) ps[m][r] = s[m][0][r] + s[m][1][r];
#pragma unroll
    for (int d = 1; d < 16; d <<= 1)
#pragma unroll
      for (int m = 0; m < 2; ++m)
#pragma unroll
        for (int r = 0; r < 4; ++r) ps[m][r] += __shfl_xor(ps[m][r], d);
#pragma unroll
    for (int m = 0; m < 2; ++m)
#pragma unroll
      for (int r = 0; r < 4; ++r)
        lst[m][r] = al[m][r] * lst[m][r] + ps[m][r];
#pragma unroll
    for (int m = 0; m < 2; ++m)
#pragma unroll
      for (int c = 0; c < 4; ++c)
#pragma unroll
        for (int r = 0; r < 4; ++r) o[m][c][r] *= al[m][r];

    // ---- P -> LDS (padded stride 40) -> A-fragments ----
#pragma unroll
    for (int m = 0; m < 2; ++m)
#pragma unroll
      for (int c = 0; c < 2; ++c)
#pragma unroll
        for (int r = 0; r < 4; ++r)
          p_lds[(m * 16 + lkg * 4 + r) * 40 + c * 16 + lrow] = f2bf(s[m][c][r]);
    s16x8 pa[2];
#pragma unroll
    for (int m = 0; m < 2; ++m)
      pa[m] = *(const s16x8*)&p_lds[(m * 16 + lrow) * 40 + lkg * 8];

    // ---- O += P V  (V read pre-transposed: contiguous 16B loads) ----
    s16x8 bv[4];
#pragma unroll
    for (int c2 = 0; c2 < 4; ++c2)
      bv[c2] = *(const s16x8*)&vtg[((bh << 6) + c2 * 16 + lrow) * 2048 + kv0 +
                                   lkg * 8];
#pragma unroll
    for (int m = 0; m < 2; ++m)
#pragma unroll
      for (int c2 = 0; c2 < 4; ++c2) o[m][c2] = mfma16(pa[m], bv[c2], o[m][c2]);
  }

  // ---- normalize + store y[b][t][h*64+d] bf16 ----
#pragma unroll
  for (int m = 0; m < 2; ++m) {
    float inv[4];
#pragma unroll
    for (int r = 0; r < 4; ++r) inv[r] = 1.0f / lst[m][r];
#pragma unroll
    for (int c2 = 0; c2 < 4; ++c2)
#pragma unroll
      for (int r = 0; r < 4; ++r) {
        const int tt = q0 + m * 16 + lkg * 4 + r;
        yb[((bb << 11) + tt) * 1024 + hb * 64 + c2 * 16 + lrow] =
            f2bf(o[m][c2][r] * inv[r]);
      }
  }
}

extern "C" void kernel_launch(void* const* d_in, const int* in_sizes, int n_in,
                              void* d_out, int out_size, void* d_ws,
                              size_t ws_size, hipStream_t stream) {
  const float* x = (const float*)d_in[0];
  const float* wa = (const float*)d_in[1];
  const float* wp = (const float*)d_in[2];
  float* out = (float*)d_out;
  u16* ws = (u16*)d_ws;

  u16* xb = ws;                 // [4096][1024]
  u16* wat = xb + 4194304;      // [3072][1024]
  u16* wpt = wat + 3145728;     // [1024][1024]
  u16* qg = wpt + 1048576;      // [32][2048][64]
  u16* kg = qg + 4194304;       // [32][2048][64]
  u16* vtg = kg + 4194304;      // [32][64][2048]
  u16* yb = vtg + 4194304;      // [4096][1024]

  k_cvt<<<2048, 256, 0, stream>>>(x, xb, 4194304);
  k_transpose_cvt<<<dim3(48, 16), 256, 0, stream>>>(wa, wat, 1024, 3072);
  k_transpose_cvt<<<dim3(16, 16), 256, 0, stream>>>(wp, wpt, 1024, 1024);
  k_gemm<0><<<dim3(24, 32), 256, 0, stream>>>(xb, wat, qg, kg, vtg, nullptr,
                                              4096, 3072, 1024);
  k_attn<<<dim3(64, 32), 64, 0, stream>>>(qg, kg, vtg, yb);
  k_gemm<1><<<dim3(8, 32), 256, 0, stream>>>(yb, wpt, nullptr, nullptr, nullptr,
                                             out, 4096, 1024, 1024);
}

// Round 2
// 269.127 us; speedup vs baseline: 1.2303x; 1.2303x over previous
//
#include <hip/hip_runtime.h>

using u16 = unsigned short;
using u32 = unsigned int;

typedef __attribute__((ext_vector_type(8))) short s16x8;
typedef __attribute__((ext_vector_type(8))) __bf16 bf16x8;
typedef __attribute__((ext_vector_type(4))) float f32x4;

static __device__ __forceinline__ u16 f2bf(float f) {
  u32 u = __builtin_bit_cast(u32, f);
  u32 r = u + 0x7FFFu + ((u >> 16) & 1u);
  return (u16)(r >> 16);
}

static __device__ __forceinline__ f32x4 mfma16(s16x8 a, s16x8 b, f32x4 c) {
  return __builtin_amdgcn_mfma_f32_16x16x32_bf16(
      __builtin_bit_cast(bf16x8, a), __builtin_bit_cast(bf16x8, b), c, 0, 0, 0);
}

#define GLOAD_LDS16(gp, lp)                                                    \
  __builtin_amdgcn_global_load_lds(                                            \
      (const __attribute__((address_space(1))) void*)(gp),                     \
      (__attribute__((address_space(3))) void*)(lp), 16, 0, 0)

// ---------------- f32 -> bf16 convert (vectorized) ----------------
__global__ __launch_bounds__(256) void k_cvt(const float* __restrict__ in,
                                             u16* __restrict__ out, int n) {
  int i = (blockIdx.x * 256 + threadIdx.x) * 8;
  if (i >= n) return;
  const float4 v0 = *(const float4*)(in + i);
  const float4 v1 = *(const float4*)(in + i + 4);
  s16x8 o;
  o[0] = f2bf(v0.x); o[1] = f2bf(v0.y); o[2] = f2bf(v0.z); o[3] = f2bf(v0.w);
  o[4] = f2bf(v1.x); o[5] = f2bf(v1.y); o[6] = f2bf(v1.z); o[7] = f2bf(v1.w);
  *(s16x8*)(out + i) = o;
}

// ------------- transpose + convert: src[K][N] f32 -> dst[N][K] bf16 -------------
__global__ __launch_bounds__(256) void k_transpose_cvt(const float* __restrict__ src,
                                                       u16* __restrict__ dst,
                                                       int K, int N) {
  __shared__ float tile[64][65];
  const int n0 = blockIdx.x * 64, k0 = blockIdx.y * 64;
  const int c = threadIdx.x & 63, r4 = threadIdx.x >> 6;
#pragma unroll
  for (int i = 0; i < 16; ++i) {
    int r = (i << 2) + r4;
    tile[r][c] = src[(k0 + r) * N + n0 + c];
  }
  __syncthreads();
#pragma unroll
  for (int i = 0; i < 16; ++i) {
    int r = (i << 2) + r4;
    dst[(n0 + r) * K + k0 + c] = f2bf(tile[c][r]);
  }
}

// ---------------- GEMM: C[M,N] = A[M,K] (bf16) @ BT[N,K]^T (bf16) ----------------
template <int MODE>
__global__ __launch_bounds__(256) void k_gemm(
    const u16* __restrict__ A, const u16* __restrict__ BT,
    u16* __restrict__ qg, u16* __restrict__ kg, u16* __restrict__ vtg,
    float* __restrict__ cout, int M, int N, int K) {
  __shared__ __align__(16) u16 As[128 * 32];
  __shared__ __align__(16) u16 Bs[128 * 32];
  const int t = threadIdx.x;
  const int lane = t & 63;
  const int w = t >> 6, wr = w >> 1, wc = w & 1;
  const int lrow = lane & 15, lkg = lane >> 4;
  const int m0 = blockIdx.y * 128, n0 = blockIdx.x * 128;

  const int ch1 = t + 256;
  const int ra0 = t >> 2, ca0 = (t & 3) << 3;
  const int ra1 = ch1 >> 2, ca1 = (ch1 & 3) << 3;
  const u16* gA0 = A + (m0 + ra0) * K + ca0;
  const u16* gA1 = A + (m0 + ra1) * K + ca1;
  const u16* gB0 = BT + (n0 + ra0) * K + ca0;
  const u16* gB1 = BT + (n0 + ra1) * K + ca1;
  u16* lA0 = &As[t * 8];
  u16* lA1 = &As[ch1 * 8];
  u16* lB0 = &Bs[t * 8];
  u16* lB1 = &Bs[ch1 * 8];

  f32x4 acc[4][4];
#pragma unroll
  for (int m = 0; m < 4; ++m)
#pragma unroll
    for (int n = 0; n < 4; ++n) acc[m][n] = (f32x4){0.f, 0.f, 0.f, 0.f};

  for (int k0 = 0; k0 < K; k0 += 32) {
    GLOAD_LDS16(gA0 + k0, lA0);
    GLOAD_LDS16(gA1 + k0, lA1);
    GLOAD_LDS16(gB0 + k0, lB0);
    GLOAD_LDS16(gB1 + k0, lB1);
    __syncthreads();
    s16x8 af[4], bfr[4];
#pragma unroll
    for (int m = 0; m < 4; ++m)
      af[m] = *(const s16x8*)&As[(wr * 64 + m * 16 + lrow) * 32 + lkg * 8];
#pragma unroll
    for (int n = 0; n < 4; ++n)
      bfr[n] = *(const s16x8*)&Bs[(wc * 64 + n * 16 + lrow) * 32 + lkg * 8];
#pragma unroll
    for (int m = 0; m < 4; ++m)
#pragma unroll
      for (int n = 0; n < 4; ++n) acc[m][n] = mfma16(af[m], bfr[n], acc[m][n]);
    __syncthreads();
  }

#pragma unroll
  for (int m = 0; m < 4; ++m)
#pragma unroll
    for (int n = 0; n < 4; ++n)
#pragma unroll
      for (int r = 0; r < 4; ++r) {
        const int rg = m0 + wr * 64 + m * 16 + lkg * 4 + r;
        const int cg = n0 + wc * 64 + n * 16 + lrow;
        const float v = acc[m][n][r];
        if (MODE == 0) {
          const int part = cg >> 10, rem = cg & 1023;
          const int h = rem >> 6, d = rem & 63;
          const int b = rg >> 11, tt = rg & 2047;
          const int bh = b * 16 + h;
          if (part == 0)
            qg[(bh * 2048 + tt) * 64 + d] = f2bf(v * 0.125f);
          else if (part == 1)
            kg[(bh * 2048 + tt) * 64 + d] = f2bf(v);
          else
            vtg[(bh * 64 + d) * 2048 + tt] = f2bf(v);
        } else {
          cout[rg * N + cg] = v;
        }
      }
}

// ---------------- causal flash attention (v2) ----------------
// 4 waves/block, 128 q-rows/block (32/wave), KVBLK=64.
// K and V^T staged in LDS (XOR-swizzled via pre-swizzled global source),
// double-buffered with counted vmcnt(4) + raw s_barrier.
__global__ __launch_bounds__(256) void k_attn(const u16* __restrict__ qg,
                                              const u16* __restrict__ kg,
                                              const u16* __restrict__ vtg,
                                              u16* __restrict__ yb) {
  __shared__ __align__(16) u16 Ks[2][64 * 64];
  __shared__ __align__(16) u16 Vs[2][64 * 64];
  __shared__ __align__(16) u16 Ps[4][32 * 72];
  const int t = threadIdx.x;
  const int lane = t & 63, w = t >> 6;
  const int lrow = lane & 15, lkg = lane >> 4;
  const int qs = blockIdx.x, bh = blockIdx.y;
  const int qB = qs * 128;
  const int qw0 = qB + w * 32;
  const int hb = bh & 15, bb = bh >> 4;
  const f32x4 z4 = {0.f, 0.f, 0.f, 0.f};

  const u16* kbase = kg + ((long)bh << 11) * 64;
  const u16* vbase = vtg + ((long)bh << 6) * 2048;

  // staging constants: within each 1KB issue, row = base8 + (lane>>3), chunk = lane&7
  const int srow = lane >> 3;
  const int sxor8 = ((lane & 7) ^ srow) << 3;  // permuted element offset

  // Q fragments (per-wave rows, pre-scaled by 1/8 at QKV epilogue)
  s16x8 aq[2][2];
#pragma unroll
  for (int m = 0; m < 2; ++m)
#pragma unroll
    for (int kk = 0; kk < 2; ++kk)
      aq[m][kk] = *(const s16x8*)&qg[((bh << 11) + qw0 + m * 16 + lrow) * 64 +
                                     kk * 32 + lkg * 8];

  f32x4 o[2][4];
  float mst[2][4], lst[2][4];
#pragma unroll
  for (int m = 0; m < 2; ++m) {
#pragma unroll
    for (int d = 0; d < 4; ++d) o[m][d] = z4;
#pragma unroll
    for (int r = 0; r < 4; ++r) { mst[m][r] = -3e38f; lst[m][r] = 0.f; }
  }

  const int nt = 2 * qs + 2;

#define STAGE(BUF, TT)                                                         \
  {                                                                            \
    const int kv0s = (TT) << 6;                                                \
    _Pragma("unroll") for (int i = 0; i < 2; ++i) {                            \
      const int rr = ((i * 4 + w) << 3) + srow;                                \
      const int dst = (((i * 4 + w) << 6) + lane) << 3;                        \
      GLOAD_LDS16(kbase + ((kv0s + rr) << 6) + sxor8, &Ks[BUF][dst]);          \
      GLOAD_LDS16(vbase + ((long)rr << 11) + kv0s + sxor8, &Vs[BUF][dst]);     \
    }                                                                          \
  }

  STAGE(0, 0);
  int buf = 0;
  for (int tt = 0; tt < nt; ++tt) {
    const int kv0 = tt << 6;
    if (tt + 1 < nt) {
      STAGE(buf ^ 1, tt + 1);
      asm volatile("s_waitcnt vmcnt(4)" ::: "memory");
    } else {
      asm volatile("s_waitcnt vmcnt(0)" ::: "memory");
    }
    __builtin_amdgcn_s_barrier();
    __builtin_amdgcn_sched_barrier(0);

    if (kv0 < qw0 + 32) {
      // ---- S = Q K^T ----
      f32x4 s[2][4];
      __builtin_amdgcn_s_setprio(1);
#pragma unroll
      for (int c = 0; c < 4; ++c) {
        const int krow = c * 16 + lrow;
        const int sw = lrow & 7;
        s16x8 bk0 = *(const s16x8*)&Ks[buf][krow * 64 + ((lkg ^ sw) << 3)];
        s16x8 bk1 = *(const s16x8*)&Ks[buf][krow * 64 + (((4 + lkg) ^ sw) << 3)];
#pragma unroll
        for (int m = 0; m < 2; ++m)
          s[m][c] = mfma16(aq[m][1], bk1, mfma16(aq[m][0], bk0, z4));
      }
      __builtin_amdgcn_s_setprio(0);

      if (kv0 + 64 > qw0) {  // tile touches/crosses the diagonal: mask
#pragma unroll
        for (int m = 0; m < 2; ++m) {
          const int rg = qw0 + m * 16 + lkg * 4;
#pragma unroll
          for (int c = 0; c < 4; ++c) {
            const int cg = kv0 + c * 16 + lrow;
#pragma unroll
            for (int r = 0; r < 4; ++r)
              if (cg > rg + r) s[m][c][r] = -3e38f;
          }
        }
      }

      // ---- online softmax (rows in 16-lane groups) ----
      float pmax[2][4], al[2][4], ps[2][4];
#pragma unroll
      for (int m = 0; m < 2; ++m)
#pragma unroll
        for (int r = 0; r < 4; ++r)
          pmax[m][r] = fmaxf(fmaxf(s[m][0][r], s[m][1][r]),
                             fmaxf(s[m][2][r], s[m][3][r]));
#pragma unroll
      for (int d = 1; d < 16; d <<= 1)
#pragma unroll
        for (int m = 0; m < 2; ++m)
#pragma unroll
          for (int r = 0; r < 4; ++r)
            pmax[m][r] = fmaxf(pmax[m][r], __shfl_xor(pmax[m][r], d));
#pragma unroll
      for (int m = 0; m < 2; ++m)
#pragma unroll
        for (int r = 0; r < 4; ++r) {
          const float mn = fmaxf(mst[m][r], pmax[m][r]);
          al[m][r] = __expf(mst[m][r] - mn);
          mst[m][r] = mn;
        }
#pragma unroll
      for (int m = 0; m < 2; ++m)
#pragma unroll
        for (int c = 0; c < 4; ++c)
#pragma unroll
          for (int r = 0; r < 4; ++r)
            s[m][c][r] = __expf(s[m][c][r] - mst[m][r]);
#pragma unroll
      for (int m = 0; m < 2; ++m)
#pragma unroll
        for (int r = 0; r < 4; ++r)
          ps[m][r] = (s[m][0][r] + s[m][1][r]) + (s[m][2][r] + s[m][3][r]);
#pragma unroll
      for (int d = 1; d < 16; d <<= 1)
#pragma unroll
        for (int m = 0; m < 2; ++m)
#pragma unroll
          for (int r = 0; r < 4; ++r) ps[m][r] += __shfl_xor(ps[m][r], d);
#pragma unroll
      for (int m = 0; m < 2; ++m)
#pragma unroll
        for (int r = 0; r < 4; ++r)
          lst[m][r] = al[m][r] * lst[m][r] + ps[m][r];
#pragma unroll
      for (int m = 0; m < 2; ++m)
#pragma unroll
        for (int d = 0; d < 4; ++d)
#pragma unroll
          for (int r = 0; r < 4; ++r) o[m][d][r] *= al[m][r];

      // ---- P -> per-wave LDS (stride 72) -> A-fragments ----
#pragma unroll
      for (int m = 0; m < 2; ++m)
#pragma unroll
        for (int c = 0; c < 4; ++c)
#pragma unroll
          for (int r = 0; r < 4; ++r)
            Ps[w][(m * 16 + lkg * 4 + r) * 72 + c * 16 + lrow] =
                f2bf(s[m][c][r]);
      s16x8 pa[2][2];
#pragma unroll
      for (int m = 0; m < 2; ++m)
#pragma unroll
        for (int ks = 0; ks < 2; ++ks)
          pa[m][ks] =
              *(const s16x8*)&Ps[w][(m * 16 + lrow) * 72 + ks * 32 + lkg * 8];

      // ---- O += P V ----
      __builtin_amdgcn_s_setprio(1);
#pragma unroll
      for (int d = 0; d < 4; ++d) {
        const int vrow = d * 16 + lrow;
        const int sw = lrow & 7;
        s16x8 bv0 = *(const s16x8*)&Vs[buf][vrow * 64 + ((lkg ^ sw) << 3)];
        s16x8 bv1 = *(const s16x8*)&Vs[buf][vrow * 64 + (((4 + lkg) ^ sw) << 3)];
#pragma unroll
        for (int m = 0; m < 2; ++m)
          o[m][d] = mfma16(pa[m][1], bv1, mfma16(pa[m][0], bv0, o[m][d]));
      }
      __builtin_amdgcn_s_setprio(0);
    }

    __builtin_amdgcn_s_barrier();
    buf ^= 1;
  }

  // ---- normalize + store y[b][t][h*64+d] bf16 ----
#pragma unroll
  for (int m = 0; m < 2; ++m) {
    float inv[4];
#pragma unroll
    for (int r = 0; r < 4; ++r) inv[r] = 1.0f / lst[m][r];
#pragma unroll
    for (int d = 0; d < 4; ++d)
#pragma unroll
      for (int r = 0; r < 4; ++r) {
        const int tq = qw0 + m * 16 + lkg * 4 + r;
        yb[((bb << 11) + tq) * 1024 + hb * 64 + d * 16 + lrow] =
            f2bf(o[m][d][r] * inv[r]);
      }
  }
#undef STAGE
}

extern "C" void kernel_launch(void* const* d_in, const int* in_sizes, int n_in,
                              void* d_out, int out_size, void* d_ws,
                              size_t ws_size, hipStream_t stream) {
  const float* x = (const float*)d_in[0];
  const float* wa = (const float*)d_in[1];
  const float* wp = (const float*)d_in[2];
  float* out = (float*)d_out;
  u16* ws = (u16*)d_ws;

  u16* xb = ws;                 // [4096][1024]
  u16* wat = xb + 4194304;      // [3072][1024]
  u16* wpt = wat + 3145728;     // [1024][1024]
  u16* qg = wpt + 1048576;      // [32][2048][64]
  u16* kg = qg + 4194304;       // [32][2048][64]
  u16* vtg = kg + 4194304;      // [32][64][2048]
  u16* yb = vtg + 4194304;      // [4096][1024]

  k_cvt<<<2048, 256, 0, stream>>>(x, xb, 4194304);
  k_transpose_cvt<<<dim3(48, 16), 256, 0, stream>>>(wa, wat, 1024, 3072);
  k_transpose_cvt<<<dim3(16, 16), 256, 0, stream>>>(wp, wpt, 1024, 1024);
  k_gemm<0><<<dim3(24, 32), 256, 0, stream>>>(xb, wat, qg, kg, vtg, nullptr,
                                              4096, 3072, 1024);
  k_attn<<<dim3(16, 32), 256, 0, stream>>>(qg, kg, vtg, yb);
  k_gemm<1><<<dim3(8, 32), 256, 0, stream>>>(yb, wpt, nullptr, nullptr, nullptr,
                                             out, 4096, 1024, 1024);
}

// Round 3
// 228.487 us; speedup vs baseline: 1.4491x; 1.1779x over previous
//
#include <hip/hip_runtime.h>

using u16 = unsigned short;
using u32 = unsigned int;

typedef __attribute__((ext_vector_type(8))) short s16x8;
typedef __attribute__((ext_vector_type(4))) short s16x4;
typedef __attribute__((ext_vector_type(8))) __bf16 bf16x8;
typedef __attribute__((ext_vector_type(4))) float f32x4;

static __device__ __forceinline__ u16 f2bf(float f) {
  u32 u = __builtin_bit_cast(u32, f);
  u32 r = u + 0x7FFFu + ((u >> 16) & 1u);
  return (u16)(r >> 16);
}

static __device__ __forceinline__ f32x4 mfma16(s16x8 a, s16x8 b, f32x4 c) {
  return __builtin_amdgcn_mfma_f32_16x16x32_bf16(
      __builtin_bit_cast(bf16x8, a), __builtin_bit_cast(bf16x8, b), c, 0, 0, 0);
}

#define GLOAD_LDS16(gp, lp)                                                    \
  __builtin_amdgcn_global_load_lds(                                            \
      (const __attribute__((address_space(1))) void*)(gp),                     \
      (__attribute__((address_space(3))) void*)(lp), 16, 0, 0)

// ---------------- f32 -> bf16 convert (vectorized) ----------------
__global__ __launch_bounds__(256) void k_cvt(const float* __restrict__ in,
                                             u16* __restrict__ out, int n) {
  int i = (blockIdx.x * 256 + threadIdx.x) * 8;
  if (i >= n) return;
  const float4 v0 = *(const float4*)(in + i);
  const float4 v1 = *(const float4*)(in + i + 4);
  s16x8 o;
  o[0] = f2bf(v0.x); o[1] = f2bf(v0.y); o[2] = f2bf(v0.z); o[3] = f2bf(v0.w);
  o[4] = f2bf(v1.x); o[5] = f2bf(v1.y); o[6] = f2bf(v1.z); o[7] = f2bf(v1.w);
  *(s16x8*)(out + i) = o;
}

// ------------- transpose + convert: src[K][N] f32 -> dst[N][K] bf16 -------------
__global__ __launch_bounds__(256) void k_transpose_cvt(const float* __restrict__ src,
                                                       u16* __restrict__ dst,
                                                       int K, int N) {
  __shared__ float tile[64][65];
  const int n0 = blockIdx.x * 64, k0 = blockIdx.y * 64;
  const int c = threadIdx.x & 63, r4 = threadIdx.x >> 6;
#pragma unroll
  for (int i = 0; i < 16; ++i) {
    int r = (i << 2) + r4;
    tile[r][c] = src[(k0 + r) * N + n0 + c];
  }
  __syncthreads();
#pragma unroll
  for (int i = 0; i < 16; ++i) {
    int r = (i << 2) + r4;
    dst[(n0 + r) * K + k0 + c] = f2bf(tile[c][r]);
  }
}

// ---------------- GEMM: C[M,N] = A[M,K] (bf16) @ BT[N,K]^T (bf16) ----------------
template <int MODE>
__global__ __launch_bounds__(256) void k_gemm(
    const u16* __restrict__ A, const u16* __restrict__ BT,
    u16* __restrict__ qg, u16* __restrict__ kg, u16* __restrict__ vtg,
    float* __restrict__ cout, int M, int N, int K) {
  __shared__ __align__(16) u16 As[128 * 32];
  __shared__ __align__(16) u16 Bs[128 * 32];
  const int t = threadIdx.x;
  const int lane = t & 63;
  const int w = t >> 6, wr = w >> 1, wc = w & 1;
  const int lrow = lane & 15, lkg = lane >> 4;
  const int m0 = blockIdx.y * 128, n0 = blockIdx.x * 128;

  const int ch1 = t + 256;
  const int ra0 = t >> 2, ca0 = (t & 3) << 3;
  const int ra1 = ch1 >> 2, ca1 = (ch1 & 3) << 3;
  const u16* gA0 = A + (m0 + ra0) * K + ca0;
  const u16* gA1 = A + (m0 + ra1) * K + ca1;
  const u16* gB0 = BT + (n0 + ra0) * K + ca0;
  const u16* gB1 = BT + (n0 + ra1) * K + ca1;
  u16* lA0 = &As[t * 8];
  u16* lA1 = &As[ch1 * 8];
  u16* lB0 = &Bs[t * 8];
  u16* lB1 = &Bs[ch1 * 8];

  f32x4 acc[4][4];
#pragma unroll
  for (int m = 0; m < 4; ++m)
#pragma unroll
    for (int n = 0; n < 4; ++n) acc[m][n] = (f32x4){0.f, 0.f, 0.f, 0.f};

  for (int k0 = 0; k0 < K; k0 += 32) {
    GLOAD_LDS16(gA0 + k0, lA0);
    GLOAD_LDS16(gA1 + k0, lA1);
    GLOAD_LDS16(gB0 + k0, lB0);
    GLOAD_LDS16(gB1 + k0, lB1);
    __syncthreads();
    s16x8 af[4], bfr[4];
#pragma unroll
    for (int m = 0; m < 4; ++m)
      af[m] = *(const s16x8*)&As[(wr * 64 + m * 16 + lrow) * 32 + lkg * 8];
#pragma unroll
    for (int n = 0; n < 4; ++n)
      bfr[n] = *(const s16x8*)&Bs[(wc * 64 + n * 16 + lrow) * 32 + lkg * 8];
#pragma unroll
    for (int m = 0; m < 4; ++m)
#pragma unroll
      for (int n = 0; n < 4; ++n) acc[m][n] = mfma16(af[m], bfr[n], acc[m][n]);
    __syncthreads();
  }

#pragma unroll
  for (int m = 0; m < 4; ++m)
#pragma unroll
    for (int n = 0; n < 4; ++n)
#pragma unroll
      for (int r = 0; r < 4; ++r) {
        const int rg = m0 + wr * 64 + m * 16 + lkg * 4 + r;
        const int cg = n0 + wc * 64 + n * 16 + lrow;
        const float v = acc[m][n][r];
        if (MODE == 0) {
          const int part = cg >> 10, rem = cg & 1023;
          const int h = rem >> 6, d = rem & 63;
          const int b = rg >> 11, tt = rg & 2047;
          const int bh = b * 16 + h;
          if (part == 0)
            qg[(bh * 2048 + tt) * 64 + d] = f2bf(v * 0.18033688f);  // 1/8 * log2(e)
          else if (part == 1)
            kg[(bh * 2048 + tt) * 64 + d] = f2bf(v);
          else
            vtg[(bh * 64 + d) * 2048 + tt] = f2bf(v);
        } else {
          cout[rg * N + cg] = v;
        }
      }
}

// ---------------- causal flash attention (v3: swapped-operand MFMA) ----------------
// 4 waves/block, 128 q-rows/block (32/wave), KVBLK=64.
// S^T = mfma(K,Q): lane owns 16 P-values of ONE q-row -> 2-shfl row reduce.
// O^T = mfma(V^T,P): rescale is a per-lane scalar; stores pack 4 contig d.
// K/V LDS double-buffered (pre-swizzled global src), counted vmcnt(4), raw barriers.
// Complement q-tile pairing: co-resident blocks (id, id+256) get (qs, 15-qs).
__global__ __launch_bounds__(256) void k_attn(const u16* __restrict__ qg,
                                              const u16* __restrict__ kg,
                                              const u16* __restrict__ vtg,
                                              u16* __restrict__ yb) {
  __shared__ __align__(16) u16 Ks[2][64 * 64];
  __shared__ __align__(16) u16 Vs[2][64 * 64];
  __shared__ __align__(16) u16 Ps[4][32 * 72];
  const int t = threadIdx.x;
  const int lane = t & 63, w = t >> 6;
  const int lrow = lane & 15, lkg = lane >> 4;
  const int bx = blockIdx.x, by = blockIdx.y;
  const int qs = (by & 16) ? (15 - bx) : bx;  // long+short pair per CU
  const int bh = by;
  const int qw0 = qs * 128 + w * 32;
  const int hb = bh & 15, bb = bh >> 4;
  const int sw = lrow & 7;
  const f32x4 z4 = {0.f, 0.f, 0.f, 0.f};

  const u16* kbase = kg + ((long)bh << 11) * 64;
  const u16* vbase = vtg + ((long)bh << 6) * 2048;

  const int srow = lane >> 3;
  const int sxor8 = ((lane & 7) ^ srow) << 3;

  // Q fragments (pre-scaled by 1/8*log2e); used as MFMA B-operand
  s16x8 aq[2][2];
#pragma unroll
  for (int m = 0; m < 2; ++m)
#pragma unroll
    for (int kk = 0; kk < 2; ++kk)
      aq[m][kk] = *(const s16x8*)&qg[((bh << 11) + qw0 + m * 16 + lrow) * 64 +
                                     kk * 32 + lkg * 8];

  f32x4 o[2][4];  // O^T: lane holds O[q=qw0+16m+lrow][d=16c2+4lkg+r]
  float mst[2], lst[2];
#pragma unroll
  for (int m = 0; m < 2; ++m) {
#pragma unroll
    for (int d = 0; d < 4; ++d) o[m][d] = z4;
    mst[m] = -3e38f;
    lst[m] = 0.f;
  }

  const int nt = 2 * qs + 2;

#define STAGE(BUF, TT)                                                         \
  {                                                                            \
    const int kv0s = (TT) << 6;                                                \
    _Pragma("unroll") for (int i = 0; i < 2; ++i) {                            \
      const int rr = ((i * 4 + w) << 3) + srow;                                \
      const int dst = (((i * 4 + w) << 6) + lane) << 3;                        \
      GLOAD_LDS16(kbase + ((kv0s + rr) << 6) + sxor8, &Ks[BUF][dst]);          \
      GLOAD_LDS16(vbase + ((long)rr << 11) + kv0s + sxor8, &Vs[BUF][dst]);     \
    }                                                                          \
  }

  STAGE(0, 0);
  int buf = 0;
  for (int tt = 0; tt < nt; ++tt) {
    const int kv0 = tt << 6;
    if (tt + 1 < nt) {
      STAGE(buf ^ 1, tt + 1);
      asm volatile("s_waitcnt vmcnt(4)" ::: "memory");
    } else {
      asm volatile("s_waitcnt vmcnt(0)" ::: "memory");
    }
    __builtin_amdgcn_s_barrier();
    __builtin_amdgcn_sched_barrier(0);

    if (kv0 < qw0 + 32) {
      // ---- S^T = K Q^T : s[m][c][r] = S[q=qw0+16m+lrow][kv=kv0+16c+4lkg+r] ----
      f32x4 s[2][4];
      __builtin_amdgcn_s_setprio(1);
#pragma unroll
      for (int c = 0; c < 4; ++c) {
        const int krow = c * 16 + lrow;
        s16x8 bk0 = *(const s16x8*)&Ks[buf][krow * 64 + ((lkg ^ sw) << 3)];
        s16x8 bk1 = *(const s16x8*)&Ks[buf][krow * 64 + (((4 + lkg) ^ sw) << 3)];
#pragma unroll
        for (int m = 0; m < 2; ++m)
          s[m][c] = mfma16(bk1, aq[m][1], mfma16(bk0, aq[m][0], z4));
      }
      __builtin_amdgcn_s_setprio(0);

      if (kv0 + 64 > qw0) {  // tile touches the diagonal: causal mask
#pragma unroll
        for (int m = 0; m < 2; ++m) {
          const int qrow = qw0 + m * 16 + lrow;
#pragma unroll
          for (int c = 0; c < 4; ++c) {
            const int kvb = kv0 + c * 16 + lkg * 4;
#pragma unroll
            for (int r = 0; r < 4; ++r)
              if (kvb + r > qrow) s[m][c][r] = -3e38f;
          }
        }
      }

      // ---- online softmax: lane-local row, 2-shfl combine ----
      u16* PW = Ps[w];
#pragma unroll
      for (int m = 0; m < 2; ++m) {
        float lm = s[m][0][0];
#pragma unroll
        for (int c = 0; c < 4; ++c)
#pragma unroll
          for (int r = 0; r < 4; ++r) lm = fmaxf(lm, s[m][c][r]);
        lm = fmaxf(lm, __shfl_xor(lm, 16));
        lm = fmaxf(lm, __shfl_xor(lm, 32));
        const float mn = fmaxf(mst[m], lm);
        const float alm = exp2f(mst[m] - mn);
        mst[m] = mn;
        float ss = 0.f;
#pragma unroll
        for (int c = 0; c < 4; ++c)
#pragma unroll
          for (int r = 0; r < 4; ++r) {
            const float p = exp2f(s[m][c][r] - mn);
            s[m][c][r] = p;
            ss += p;
          }
        ss += __shfl_xor(ss, 16);
        ss += __shfl_xor(ss, 32);
        lst[m] = alm * lst[m] + ss;
#pragma unroll
        for (int d = 0; d < 4; ++d) o[m][d] *= alm;
        // P -> per-wave LDS, 4-contig b64 writes (row = q-local)
#pragma unroll
        for (int c = 0; c < 4; ++c) {
          s16x4 pk;
#pragma unroll
          for (int r = 0; r < 4; ++r) pk[r] = f2bf(s[m][c][r]);
          *(s16x4*)&PW[(m * 16 + lrow) * 72 + c * 16 + lkg * 4] = pk;
        }
      }

      // ---- B-fragments of P: contiguous b128 reads ----
      s16x8 pb[2][2];
#pragma unroll
      for (int m = 0; m < 2; ++m)
#pragma unroll
        for (int kk = 0; kk < 2; ++kk)
          pb[m][kk] =
              *(const s16x8*)&PW[(m * 16 + lrow) * 72 + kk * 32 + lkg * 8];

      // ---- O^T += V^T P^T ----
      __builtin_amdgcn_s_setprio(1);
#pragma unroll
      for (int d = 0; d < 4; ++d) {
        const int vrow = d * 16 + lrow;
        s16x8 bv0 = *(const s16x8*)&Vs[buf][vrow * 64 + ((lkg ^ sw) << 3)];
        s16x8 bv1 = *(const s16x8*)&Vs[buf][vrow * 64 + (((4 + lkg) ^ sw) << 3)];
#pragma unroll
        for (int m = 0; m < 2; ++m)
          o[m][d] = mfma16(bv1, pb[m][1], mfma16(bv0, pb[m][0], o[m][d]));
      }
      __builtin_amdgcn_s_setprio(0);
    }

    __builtin_amdgcn_s_barrier();
    buf ^= 1;
  }

  // ---- normalize + store: 4-contig d per (m,c2) -> 8B stores ----
#pragma unroll
  for (int m = 0; m < 2; ++m) {
    const float inv = 1.0f / lst[m];
    const int q = qw0 + m * 16 + lrow;
    u16* yrow = yb + ((long)((bb << 11) + q)) * 1024 + hb * 64;
#pragma unroll
    for (int d = 0; d < 4; ++d) {
      s16x4 pk;
#pragma unroll
      for (int r = 0; r < 4; ++r) pk[r] = f2bf(o[m][d][r] * inv);
      *(s16x4*)&yrow[d * 16 + lkg * 4] = pk;
    }
  }
#undef STAGE
}

extern "C" void kernel_launch(void* const* d_in, const int* in_sizes, int n_in,
                              void* d_out, int out_size, void* d_ws,
                              size_t ws_size, hipStream_t stream) {
  const float* x = (const float*)d_in[0];
  const float* wa = (const float*)d_in[1];
  const float* wp = (const float*)d_in[2];
  float* out = (float*)d_out;
  u16* ws = (u16*)d_ws;

  u16* xb = ws;                 // [4096][1024]
  u16* wat = xb + 4194304;      // [3072][1024]
  u16* wpt = wat + 3145728;     // [1024][1024]
  u16* qg = wpt + 1048576;      // [32][2048][64]
  u16* kg = qg + 4194304;       // [32][2048][64]
  u16* vtg = kg + 4194304;      // [32][64][2048]
  u16* yb = vtg + 4194304;      // [4096][1024]

  k_cvt<<<2048, 256, 0, stream>>>(x, xb, 4194304);
  k_transpose_cvt<<<dim3(48, 16), 256, 0, stream>>>(wa, wat, 1024, 3072);
  k_transpose_cvt<<<dim3(16, 16), 256, 0, stream>>>(wp, wpt, 1024, 1024);
  k_gemm<0><<<dim3(24, 32), 256, 0, stream>>>(xb, wat, qg, kg, vtg, nullptr,
                                              4096, 3072, 1024);
  k_attn<<<dim3(16, 32), 256, 0, stream>>>(qg, kg, vtg, yb);
  k_gemm<1><<<dim3(8, 32), 256, 0, stream>>>(yb, wpt, nullptr, nullptr, nullptr,
                                             out, 4096, 1024, 1024);
}

// Round 6
// 224.208 us; speedup vs baseline: 1.4767x; 1.0191x over previous
//
#include <hip/hip_runtime.h>

using u16 = unsigned short;
using u32 = unsigned int;

typedef __attribute__((ext_vector_type(8))) short s16x8;
typedef __attribute__((ext_vector_type(4))) short s16x4;
typedef __attribute__((ext_vector_type(8))) __bf16 bf16x8;
typedef __attribute__((ext_vector_type(4))) float f32x4;

static __device__ __forceinline__ u16 f2bf(float f) {
  u32 u = __builtin_bit_cast(u32, f);
  u32 r = u + 0x7FFFu + ((u >> 16) & 1u);
  return (u16)(r >> 16);
}

static __device__ __forceinline__ f32x4 mfma16(s16x8 a, s16x8 b, f32x4 c) {
  return __builtin_amdgcn_mfma_f32_16x16x32_bf16(
      __builtin_bit_cast(bf16x8, a), __builtin_bit_cast(bf16x8, b), c, 0, 0, 0);
}

#define GLOAD_LDS16(gp, lp)                                                    \
  __builtin_amdgcn_global_load_lds(                                            \
      (const __attribute__((address_space(1))) void*)(gp),                     \
      (__attribute__((address_space(3))) void*)(lp), 16, 0, 0)

// ---------------- f32 -> bf16 convert (vectorized) ----------------
__global__ __launch_bounds__(256) void k_cvt(const float* __restrict__ in,
                                             u16* __restrict__ out, int n) {
  int i = (blockIdx.x * 256 + threadIdx.x) * 8;
  if (i >= n) return;
  const float4 v0 = *(const float4*)(in + i);
  const float4 v1 = *(const float4*)(in + i + 4);
  s16x8 o;
  o[0] = f2bf(v0.x); o[1] = f2bf(v0.y); o[2] = f2bf(v0.z); o[3] = f2bf(v0.w);
  o[4] = f2bf(v1.x); o[5] = f2bf(v1.y); o[6] = f2bf(v1.z); o[7] = f2bf(v1.w);
  *(s16x8*)(out + i) = o;
}

// ------------- transpose + convert: src[K][N] f32 -> dst[N][K] bf16 -------------
__global__ __launch_bounds__(256) void k_transpose_cvt(const float* __restrict__ src,
                                                       u16* __restrict__ dst,
                                                       int K, int N) {
  __shared__ float tile[64][65];
  const int n0 = blockIdx.x * 64, k0 = blockIdx.y * 64;
  const int c = threadIdx.x & 63, r4 = threadIdx.x >> 6;
#pragma unroll
  for (int i = 0; i < 16; ++i) {
    int r = (i << 2) + r4;
    tile[r][c] = src[(k0 + r) * N + n0 + c];
  }
  __syncthreads();
#pragma unroll
  for (int i = 0; i < 16; ++i) {
    int r = (i << 2) + r4;
    dst[(n0 + r) * K + k0 + c] = f2bf(tile[c][r]);
  }
}

// ---------------- GEMM: C[M,N] = A[M,K] (bf16) @ BT[N,K]^T (bf16) ----------------
// MODE 0 (QKV): part is BLOCK-uniform (N-tile of 128 never straddles the 1024
// boundaries). q/k: direct stores. v: transpose 128x128 tile through LDS so
// vT[d][t] rows are written with contiguous 16B stores (the old per-element
// scatter had 2B stores at 4KB lane stride -> ~16-32x sector amplification).
// MODE 1: plain f32 C store.
template <int MODE>
__global__ __launch_bounds__(256) void k_gemm(
    const u16* __restrict__ A, const u16* __restrict__ BT,
    u16* __restrict__ qg, u16* __restrict__ kg, u16* __restrict__ vtg,
    float* __restrict__ cout, int M, int N, int K) {
  __shared__ __align__(16) u16 As[128 * 32];
  __shared__ __align__(16) u16 Bs[128 * 32];
  __shared__ __align__(16) u16 Ct[(MODE == 0) ? (128 * 132) : 8];
  const int t = threadIdx.x;
  const int lane = t & 63;
  const int w = t >> 6, wr = w >> 1, wc = w & 1;
  const int lrow = lane & 15, lkg = lane >> 4;
  const int m0 = blockIdx.y * 128, n0 = blockIdx.x * 128;

  const int ch1 = t + 256;
  const int ra0 = t >> 2, ca0 = (t & 3) << 3;
  const int ra1 = ch1 >> 2, ca1 = (ch1 & 3) << 3;
  const u16* gA0 = A + (m0 + ra0) * K + ca0;
  const u16* gA1 = A + (m0 + ra1) * K + ca1;
  const u16* gB0 = BT + (n0 + ra0) * K + ca0;
  const u16* gB1 = BT + (n0 + ra1) * K + ca1;
  u16* lA0 = &As[t * 8];
  u16* lA1 = &As[ch1 * 8];
  u16* lB0 = &Bs[t * 8];
  u16* lB1 = &Bs[ch1 * 8];

  f32x4 acc[4][4];
#pragma unroll
  for (int m = 0; m < 4; ++m)
#pragma unroll
    for (int n = 0; n < 4; ++n) acc[m][n] = (f32x4){0.f, 0.f, 0.f, 0.f};

  for (int k0 = 0; k0 < K; k0 += 32) {
    GLOAD_LDS16(gA0 + k0, lA0);
    GLOAD_LDS16(gA1 + k0, lA1);
    GLOAD_LDS16(gB0 + k0, lB0);
    GLOAD_LDS16(gB1 + k0, lB1);
    __syncthreads();
    s16x8 af[4], bfr[4];
#pragma unroll
    for (int m = 0; m < 4; ++m)
      af[m] = *(const s16x8*)&As[(wr * 64 + m * 16 + lrow) * 32 + lkg * 8];
#pragma unroll
    for (int n = 0; n < 4; ++n)
      bfr[n] = *(const s16x8*)&Bs[(wc * 64 + n * 16 + lrow) * 32 + lkg * 8];
#pragma unroll
    for (int m = 0; m < 4; ++m)
#pragma unroll
      for (int n = 0; n < 4; ++n) acc[m][n] = mfma16(af[m], bfr[n], acc[m][n]);
    __syncthreads();
  }

  if (MODE == 0) {
    const int part = n0 >> 10;  // block-uniform: 0=q, 1=k, 2=v
    const int b = m0 >> 11;
    const int tt0 = m0 & 2047;
    if (part < 2) {
      // q / k: row = t (coalesced-ish 2B x 16-lane = 32B chunks)
#pragma unroll
      for (int m = 0; m < 4; ++m)
#pragma unroll
        for (int n = 0; n < 4; ++n)
#pragma unroll
          for (int r = 0; r < 4; ++r) {
            const int tl = wr * 64 + m * 16 + lkg * 4 + r;
            const int rem = (n0 & 1023) + wc * 64 + n * 16 + lrow;
            const int h = rem >> 6, d = rem & 63;
            const int bh = b * 16 + h;
            const float v = acc[m][n][r];
            if (part == 0)
              qg[(bh * 2048 + tt0 + tl) * 64 + d] = f2bf(v * 0.18033688f);
            else
              kg[(bh * 2048 + tt0 + tl) * 64 + d] = f2bf(v);
          }
    } else {
      // v: C^T via LDS, then contiguous vT-row stores
#pragma unroll
      for (int m = 0; m < 4; ++m)
#pragma unroll
        for (int n = 0; n < 4; ++n) {
          const int cl2 = wc * 64 + n * 16 + lrow;        // d-local
          const int tl = wr * 64 + m * 16 + lkg * 4;      // t-local (4 contig)
          s16x4 pk;
#pragma unroll
          for (int r = 0; r < 4; ++r) pk[r] = f2bf(acc[m][n][r]);
          *(s16x4*)&Ct[cl2 * 132 + tl] = pk;
        }
      __syncthreads();
      const long vrow0 = (long)b * 1024 + (n0 & 1023);
      const int cl = t >> 1;           // d-local row 0..127
      const int ch = (t & 1) << 6;     // t-half 0 / 64
      const u16* csrc = &Ct[cl * 132 + ch];
      u16* vdst = vtg + (vrow0 + cl) * 2048 + tt0 + ch;
#pragma unroll
      for (int j = 0; j < 8; ++j) {
        const s16x4 a4 = *(const s16x4*)&csrc[j * 8];
        const s16x4 b4 = *(const s16x4*)&csrc[j * 8 + 4];
        s16x8 v8;
        v8[0] = a4[0]; v8[1] = a4[1]; v8[2] = a4[2]; v8[3] = a4[3];
        v8[4] = b4[0]; v8[5] = b4[1]; v8[6] = b4[2]; v8[7] = b4[3];
        *(s16x8*)&vdst[j * 8] = v8;
      }
    }
  } else {
#pragma unroll
    for (int m = 0; m < 4; ++m)
#pragma unroll
      for (int n = 0; n < 4; ++n)
#pragma unroll
        for (int r = 0; r < 4; ++r) {
          const int rg = m0 + wr * 64 + m * 16 + lkg * 4 + r;
          const int cg = n0 + wc * 64 + n * 16 + lrow;
          cout[rg * N + cg] = acc[m][n][r];
        }
  }
}

// ---------------- causal flash attention (verbatim R3 — known good) ----------------
__global__ __launch_bounds__(256) void k_attn(const u16* __restrict__ qg,
                                              const u16* __restrict__ kg,
                                              const u16* __restrict__ vtg,
                                              u16* __restrict__ yb) {
  __shared__ __align__(16) u16 Ks[2][64 * 64];
  __shared__ __align__(16) u16 Vs[2][64 * 64];
  __shared__ __align__(16) u16 Ps[4][32 * 72];
  const int t = threadIdx.x;
  const int lane = t & 63, w = t >> 6;
  const int lrow = lane & 15, lkg = lane >> 4;
  const int bx = blockIdx.x, by = blockIdx.y;
  const int qs = (by & 16) ? (15 - bx) : bx;  // long+short pair per CU
  const int bh = by;
  const int qw0 = qs * 128 + w * 32;
  const int hb = bh & 15, bb = bh >> 4;
  const int sw = lrow & 7;
  const f32x4 z4 = {0.f, 0.f, 0.f, 0.f};

  const u16* kbase = kg + ((long)bh << 11) * 64;
  const u16* vbase = vtg + ((long)bh << 6) * 2048;

  const int srow = lane >> 3;
  const int sxor8 = ((lane & 7) ^ srow) << 3;

  // Q fragments (pre-scaled by 1/8*log2e); used as MFMA B-operand
  s16x8 aq[2][2];
#pragma unroll
  for (int m = 0; m < 2; ++m)
#pragma unroll
    for (int kk = 0; kk < 2; ++kk)
      aq[m][kk] = *(const s16x8*)&qg[((bh << 11) + qw0 + m * 16 + lrow) * 64 +
                                     kk * 32 + lkg * 8];

  f32x4 o[2][4];  // O^T: lane holds O[q=qw0+16m+lrow][d=16c2+4lkg+r]
  float mst[2], lst[2];
#pragma unroll
  for (int m = 0; m < 2; ++m) {
#pragma unroll
    for (int d = 0; d < 4; ++d) o[m][d] = z4;
    mst[m] = -3e38f;
    lst[m] = 0.f;
  }

  const int nt = 2 * qs + 2;

#define STAGE(BUF, TT)                                                         \
  {                                                                            \
    const int kv0s = (TT) << 6;                                                \
    _Pragma("unroll") for (int i = 0; i < 2; ++i) {                            \
      const int rr = ((i * 4 + w) << 3) + srow;                                \
      const int dst = (((i * 4 + w) << 6) + lane) << 3;                        \
      GLOAD_LDS16(kbase + ((kv0s + rr) << 6) + sxor8, &Ks[BUF][dst]);          \
      GLOAD_LDS16(vbase + ((long)rr << 11) + kv0s + sxor8, &Vs[BUF][dst]);     \
    }                                                                          \
  }

  STAGE(0, 0);
  int buf = 0;
  for (int tt = 0; tt < nt; ++tt) {
    const int kv0 = tt << 6;
    if (tt + 1 < nt) {
      STAGE(buf ^ 1, tt + 1);
      asm volatile("s_waitcnt vmcnt(4)" ::: "memory");
    } else {
      asm volatile("s_waitcnt vmcnt(0)" ::: "memory");
    }
    __builtin_amdgcn_s_barrier();
    __builtin_amdgcn_sched_barrier(0);

    if (kv0 < qw0 + 32) {
      // ---- S^T = K Q^T : s[m][c][r] = S[q=qw0+16m+lrow][kv=kv0+16c+4lkg+r] ----
      f32x4 s[2][4];
      __builtin_amdgcn_s_setprio(1);
#pragma unroll
      for (int c = 0; c < 4; ++c) {
        const int krow = c * 16 + lrow;
        s16x8 bk0 = *(const s16x8*)&Ks[buf][krow * 64 + ((lkg ^ sw) << 3)];
        s16x8 bk1 = *(const s16x8*)&Ks[buf][krow * 64 + (((4 + lkg) ^ sw) << 3)];
#pragma unroll
        for (int m = 0; m < 2; ++m)
          s[m][c] = mfma16(bk1, aq[m][1], mfma16(bk0, aq[m][0], z4));
      }
      __builtin_amdgcn_s_setprio(0);

      if (kv0 + 64 > qw0) {  // tile touches the diagonal: causal mask
#pragma unroll
        for (int m = 0; m < 2; ++m) {
          const int qrow = qw0 + m * 16 + lrow;
#pragma unroll
          for (int c = 0; c < 4; ++c) {
            const int kvb = kv0 + c * 16 + lkg * 4;
#pragma unroll
            for (int r = 0; r < 4; ++r)
              if (kvb + r > qrow) s[m][c][r] = -3e38f;
          }
        }
      }

      // ---- online softmax: lane-local row, 2-shfl combine ----
      u16* PW = Ps[w];
#pragma unroll
      for (int m = 0; m < 2; ++m) {
        float lm = s[m][0][0];
#pragma unroll
        for (int c = 0; c < 4; ++c)
#pragma unroll
          for (int r = 0; r < 4; ++r) lm = fmaxf(lm, s[m][c][r]);
        lm = fmaxf(lm, __shfl_xor(lm, 16));
        lm = fmaxf(lm, __shfl_xor(lm, 32));
        const float mn = fmaxf(mst[m], lm);
        const float alm = exp2f(mst[m] - mn);
        mst[m] = mn;
        float ss = 0.f;
#pragma unroll
        for (int c = 0; c < 4; ++c)
#pragma unroll
          for (int r = 0; r < 4; ++r) {
            const float p = exp2f(s[m][c][r] - mn);
            s[m][c][r] = p;
            ss += p;
          }
        ss += __shfl_xor(ss, 16);
        ss += __shfl_xor(ss, 32);
        lst[m] = alm * lst[m] + ss;
#pragma unroll
        for (int d = 0; d < 4; ++d) o[m][d] *= alm;
        // P -> per-wave LDS, 4-contig b64 writes (row = q-local)
#pragma unroll
        for (int c = 0; c < 4; ++c) {
          s16x4 pk;
#pragma unroll
          for (int r = 0; r < 4; ++r) pk[r] = f2bf(s[m][c][r]);
          *(s16x4*)&PW[(m * 16 + lrow) * 72 + c * 16 + lkg * 4] = pk;
        }
      }

      // ---- B-fragments of P: contiguous b128 reads ----
      s16x8 pb[2][2];
#pragma unroll
      for (int m = 0; m < 2; ++m)
#pragma unroll
        for (int kk = 0; kk < 2; ++kk)
          pb[m][kk] =
              *(const s16x8*)&PW[(m * 16 + lrow) * 72 + kk * 32 + lkg * 8];

      // ---- O^T += V^T P^T ----
      __builtin_amdgcn_s_setprio(1);
#pragma unroll
      for (int d = 0; d < 4; ++d) {
        const int vrow = d * 16 + lrow;
        s16x8 bv0 = *(const s16x8*)&Vs[buf][vrow * 64 + ((lkg ^ sw) << 3)];
        s16x8 bv1 = *(const s16x8*)&Vs[buf][vrow * 64 + (((4 + lkg) ^ sw) << 3)];
#pragma unroll
        for (int m = 0; m < 2; ++m)
          o[m][d] = mfma16(bv1, pb[m][1], mfma16(bv0, pb[m][0], o[m][d]));
      }
      __builtin_amdgcn_s_setprio(0);
    }

    __builtin_amdgcn_s_barrier();
    buf ^= 1;
  }

  // ---- normalize + store: 4-contig d per (m,c2) -> 8B stores ----
#pragma unroll
  for (int m = 0; m < 2; ++m) {
    const float inv = 1.0f / lst[m];
    const int q = qw0 + m * 16 + lrow;
    u16* yrow = yb + ((long)((bb << 11) + q)) * 1024 + hb * 64;
#pragma unroll
    for (int d = 0; d < 4; ++d) {
      s16x4 pk;
#pragma unroll
      for (int r = 0; r < 4; ++r) pk[r] = f2bf(o[m][d][r] * inv);
      *(s16x4*)&yrow[d * 16 + lkg * 4] = pk;
    }
  }
#undef STAGE
}

extern "C" void kernel_launch(void* const* d_in, const int* in_sizes, int n_in,
                              void* d_out, int out_size, void* d_ws,
                              size_t ws_size, hipStream_t stream) {
  const float* x = (const float*)d_in[0];
  const float* wa = (const float*)d_in[1];
  const float* wp = (const float*)d_in[2];
  float* out = (float*)d_out;
  u16* ws = (u16*)d_ws;

  u16* xb = ws;                 // [4096][1024]
  u16* wat = xb + 4194304;      // [3072][1024]
  u16* wpt = wat + 3145728;     // [1024][1024]
  u16* qg = wpt + 1048576;      // [32][2048][64]
  u16* kg = qg + 4194304;       // [32][2048][64]
  u16* vtg = kg + 4194304;      // [32][64][2048]
  u16* yb = vtg + 4194304;      // [4096][1024]

  k_cvt<<<2048, 256, 0, stream>>>(x, xb, 4194304);
  k_transpose_cvt<<<dim3(48, 16), 256, 0, stream>>>(wa, wat, 1024, 3072);
  k_transpose_cvt<<<dim3(16, 16), 256, 0, stream>>>(wp, wpt, 1024, 1024);
  k_gemm<0><<<dim3(24, 32), 256, 0, stream>>>(xb, wat, qg, kg, vtg, nullptr,
                                              4096, 3072, 1024);
  k_attn<<<dim3(16, 32), 256, 0, stream>>>(qg, kg, vtg, yb);
  k_gemm<1><<<dim3(8, 32), 256, 0, stream>>>(yb, wpt, nullptr, nullptr, nullptr,
                                             out, 4096, 1024, 1024);
}

// Round 8
// 214.845 us; speedup vs baseline: 1.5411x; 1.0436x over previous
//
#include <hip/hip_runtime.h>
#include <hip/hip_bf16.h>

using u16 = unsigned short;
using u32 = unsigned int;

typedef __attribute__((ext_vector_type(8))) short s16x8;
typedef __attribute__((ext_vector_type(4))) short s16x4;
typedef __attribute__((ext_vector_type(8))) __bf16 bf16x8;
typedef __attribute__((ext_vector_type(4))) float f32x4;
typedef __attribute__((ext_vector_type(2))) unsigned u32x2;

static __device__ __forceinline__ u16 f2bf(float f) {
  u32 u = __builtin_bit_cast(u32, f);
  u32 r = u + 0x7FFFu + ((u >> 16) & 1u);
  return (u16)(r >> 16);
}

// pack 2 f32 -> u32 of 2 bf16 via the library (compiler emits v_cvt_pk_bf16_f32)
static __device__ __forceinline__ u32 pk2bf(float lo, float hi) {
  __hip_bfloat162 h = __float22bfloat162_rn(make_float2(lo, hi));
  u32 r;
  __builtin_memcpy(&r, &h, 4);  // __hip_bfloat162 not trivially copyable -> no bit_cast
  return r;
}

static __device__ __forceinline__ f32x4 mfma16(s16x8 a, s16x8 b, f32x4 c) {
  return __builtin_amdgcn_mfma_f32_16x16x32_bf16(
      __builtin_bit_cast(bf16x8, a), __builtin_bit_cast(bf16x8, b), c, 0, 0, 0);
}

#define GLOAD_LDS16(gp, lp)                                                    \
  __builtin_amdgcn_global_load_lds(                                            \
      (const __attribute__((address_space(1))) void*)(gp),                     \
      (__attribute__((address_space(3))) void*)(lp), 16, 0, 0)

// ---------------- f32 -> bf16 convert (vectorized) ----------------
__global__ __launch_bounds__(256) void k_cvt(const float* __restrict__ in,
                                             u16* __restrict__ out, int n) {
  int i = (blockIdx.x * 256 + threadIdx.x) * 8;
  if (i >= n) return;
  const float4 v0 = *(const float4*)(in + i);
  const float4 v1 = *(const float4*)(in + i + 4);
  s16x8 o;
  o[0] = f2bf(v0.x); o[1] = f2bf(v0.y); o[2] = f2bf(v0.z); o[3] = f2bf(v0.w);
  o[4] = f2bf(v1.x); o[5] = f2bf(v1.y); o[6] = f2bf(v1.z); o[7] = f2bf(v1.w);
  *(s16x8*)(out + i) = o;
}

// ------------- transpose + convert: src[K][N] f32 -> dst[N][K] bf16 -------------
__global__ __launch_bounds__(256) void k_transpose_cvt(const float* __restrict__ src,
                                                       u16* __restrict__ dst,
                                                       int K, int N) {
  __shared__ float tile[64][65];
  const int n0 = blockIdx.x * 64, k0 = blockIdx.y * 64;
  const int c = threadIdx.x & 63, r4 = threadIdx.x >> 6;
#pragma unroll
  for (int i = 0; i < 16; ++i) {
    int r = (i << 2) + r4;
    tile[r][c] = src[(k0 + r) * N + n0 + c];
  }
  __syncthreads();
#pragma unroll
  for (int i = 0; i < 16; ++i) {
    int r = (i << 2) + r4;
    dst[(n0 + r) * K + k0 + c] = f2bf(tile[c][r]);
  }
}

// ---------------- GEMM (QKV): C[M,N] = A[M,K] @ BT[N,K]^T, fused epilogue ----------------
template <int MODE>
__global__ __launch_bounds__(256) void k_gemm(
    const u16* __restrict__ A, const u16* __restrict__ BT,
    u16* __restrict__ qg, u16* __restrict__ kg, u16* __restrict__ vtg,
    float* __restrict__ cout, int M, int N, int K) {
  __shared__ __align__(16) u16 As[128 * 32];
  __shared__ __align__(16) u16 Bs[128 * 32];
  __shared__ __align__(16) u16 Ct[(MODE == 0) ? (128 * 132) : 8];
  const int t = threadIdx.x;
  const int lane = t & 63;
  const int w = t >> 6, wr = w >> 1, wc = w & 1;
  const int lrow = lane & 15, lkg = lane >> 4;
  const int m0 = blockIdx.y * 128, n0 = blockIdx.x * 128;

  const int ch1 = t + 256;
  const int ra0 = t >> 2, ca0 = (t & 3) << 3;
  const int ra1 = ch1 >> 2, ca1 = (ch1 & 3) << 3;
  const u16* gA0 = A + (m0 + ra0) * K + ca0;
  const u16* gA1 = A + (m0 + ra1) * K + ca1;
  const u16* gB0 = BT + (n0 + ra0) * K + ca0;
  const u16* gB1 = BT + (n0 + ra1) * K + ca1;
  u16* lA0 = &As[t * 8];
  u16* lA1 = &As[ch1 * 8];
  u16* lB0 = &Bs[t * 8];
  u16* lB1 = &Bs[ch1 * 8];

  f32x4 acc[4][4];
#pragma unroll
  for (int m = 0; m < 4; ++m)
#pragma unroll
    for (int n = 0; n < 4; ++n) acc[m][n] = (f32x4){0.f, 0.f, 0.f, 0.f};

  for (int k0 = 0; k0 < K; k0 += 32) {
    GLOAD_LDS16(gA0 + k0, lA0);
    GLOAD_LDS16(gA1 + k0, lA1);
    GLOAD_LDS16(gB0 + k0, lB0);
    GLOAD_LDS16(gB1 + k0, lB1);
    __syncthreads();
    s16x8 af[4], bfr[4];
#pragma unroll
    for (int m = 0; m < 4; ++m)
      af[m] = *(const s16x8*)&As[(wr * 64 + m * 16 + lrow) * 32 + lkg * 8];
#pragma unroll
    for (int n = 0; n < 4; ++n)
      bfr[n] = *(const s16x8*)&Bs[(wc * 64 + n * 16 + lrow) * 32 + lkg * 8];
#pragma unroll
    for (int m = 0; m < 4; ++m)
#pragma unroll
      for (int n = 0; n < 4; ++n) acc[m][n] = mfma16(af[m], bfr[n], acc[m][n]);
    __syncthreads();
  }

  if (MODE == 0) {
    const int part = n0 >> 10;  // block-uniform: 0=q, 1=k, 2=v
    const int b = m0 >> 11;
    const int tt0 = m0 & 2047;
    if (part < 2) {
#pragma unroll
      for (int m = 0; m < 4; ++m)
#pragma unroll
        for (int n = 0; n < 4; ++n)
#pragma unroll
          for (int r = 0; r < 4; ++r) {
            const int tl = wr * 64 + m * 16 + lkg * 4 + r;
            const int rem = (n0 & 1023) + wc * 64 + n * 16 + lrow;
            const int h = rem >> 6, d = rem & 63;
            const int bh = b * 16 + h;
            const float v = acc[m][n][r];
            if (part == 0)
              qg[(bh * 2048 + tt0 + tl) * 64 + d] = f2bf(v * 0.18033688f);
            else
              kg[(bh * 2048 + tt0 + tl) * 64 + d] = f2bf(v);
          }
    } else {
      // v: C^T via LDS, then contiguous vT-row stores
#pragma unroll
      for (int m = 0; m < 4; ++m)
#pragma unroll
        for (int n = 0; n < 4; ++n) {
          const int cl2 = wc * 64 + n * 16 + lrow;
          const int tl = wr * 64 + m * 16 + lkg * 4;
          s16x4 pk;
#pragma unroll
          for (int r = 0; r < 4; ++r) pk[r] = f2bf(acc[m][n][r]);
          *(s16x4*)&Ct[cl2 * 132 + tl] = pk;
        }
      __syncthreads();
      const long vrow0 = (long)b * 1024 + (n0 & 1023);
      const int cl = t >> 1;
      const int ch = (t & 1) << 6;
      const u16* csrc = &Ct[cl * 132 + ch];
      u16* vdst = vtg + (vrow0 + cl) * 2048 + tt0 + ch;
#pragma unroll
      for (int j = 0; j < 8; ++j) {
        const s16x4 a4 = *(const s16x4*)&csrc[j * 8];
        const s16x4 b4 = *(const s16x4*)&csrc[j * 8 + 4];
        s16x8 v8;
        v8[0] = a4[0]; v8[1] = a4[1]; v8[2] = a4[2]; v8[3] = a4[3];
        v8[4] = b4[0]; v8[5] = b4[1]; v8[6] = b4[2]; v8[7] = b4[3];
        *(s16x8*)&vdst[j * 8] = v8;
      }
    }
  } else {
#pragma unroll
    for (int m = 0; m < 4; ++m)
#pragma unroll
      for (int n = 0; n < 4; ++n)
#pragma unroll
        for (int r = 0; r < 4; ++r) {
          const int rg = m0 + wr * 64 + m * 16 + lkg * 4 + r;
          const int cg = n0 + wc * 64 + n * 16 + lrow;
          cout[rg * N + cg] = acc[m][n][r];
        }
  }
}

// ---------------- GEMM2 (proj): BM=64 x BN=128, f32 out — 512 blocks, 12KB LDS ----------------
__global__ __launch_bounds__(256) void k_gemm2(const u16* __restrict__ A,
                                               const u16* __restrict__ BT,
                                               float* __restrict__ cout, int M,
                                               int N, int K) {
  __shared__ __align__(16) u16 As[64 * 32];
  __shared__ __align__(16) u16 Bs[128 * 32];
  const int t = threadIdx.x;
  const int lane = t & 63;
  const int w = t >> 6, wr = w >> 1, wc = w & 1;
  const int lrow = lane & 15, lkg = lane >> 4;
  const int m0 = blockIdx.y * 64, n0 = blockIdx.x * 128;

  const int ra = t >> 2, ca = (t & 3) << 3;
  const u16* gA = A + (m0 + ra) * K + ca;
  const u16* gB0 = BT + (n0 + ra) * K + ca;
  const u16* gB1 = BT + (n0 + 64 + ra) * K + ca;
  u16* lA = &As[t * 8];
  u16* lB0 = &Bs[t * 8];
  u16* lB1 = &Bs[(t + 256) * 8];

  f32x4 acc[2][4];
#pragma unroll
  for (int m = 0; m < 2; ++m)
#pragma unroll
    for (int n = 0; n < 4; ++n) acc[m][n] = (f32x4){0.f, 0.f, 0.f, 0.f};

  for (int k0 = 0; k0 < K; k0 += 32) {
    GLOAD_LDS16(gA + k0, lA);
    GLOAD_LDS16(gB0 + k0, lB0);
    GLOAD_LDS16(gB1 + k0, lB1);
    __syncthreads();
    s16x8 af[2], bfr[4];
#pragma unroll
    for (int m = 0; m < 2; ++m)
      af[m] = *(const s16x8*)&As[(wr * 32 + m * 16 + lrow) * 32 + lkg * 8];
#pragma unroll
    for (int n = 0; n < 4; ++n)
      bfr[n] = *(const s16x8*)&Bs[(wc * 64 + n * 16 + lrow) * 32 + lkg * 8];
#pragma unroll
    for (int m = 0; m < 2; ++m)
#pragma unroll
      for (int n = 0; n < 4; ++n) acc[m][n] = mfma16(af[m], bfr[n], acc[m][n]);
    __syncthreads();
  }

#pragma unroll
  for (int m = 0; m < 2; ++m)
#pragma unroll
    for (int n = 0; n < 4; ++n)
#pragma unroll
      for (int r = 0; r < 4; ++r) {
        const int rg = m0 + wr * 32 + m * 16 + lkg * 4 + r;
        const int cg = n0 + wc * 64 + n * 16 + lrow;
        cout[rg * N + cg] = acc[m][n][r];
      }
}

// ---------------- causal flash attention (v6) ----------------
// R3 structure + MFMA row-sum (ones-trick: os[m] carries the softmax
// denominator inside the O accumulator — no sum shuffles, no lst) +
// library cvt_pk packing. Max-combine keeps the proven shfl_xor pair.
__global__ __launch_bounds__(256) void k_attn(const u16* __restrict__ qg,
                                              const u16* __restrict__ kg,
                                              const u16* __restrict__ vtg,
                                              u16* __restrict__ yb) {
  __shared__ __align__(16) u16 Ks[2][64 * 64];
  __shared__ __align__(16) u16 Vs[2][64 * 64];
  __shared__ __align__(16) u16 Ps[4][32 * 72];
  const int t = threadIdx.x;
  const int lane = t & 63, w = t >> 6;
  const int lrow = lane & 15, lkg = lane >> 4;
  const int bx = blockIdx.x, by = blockIdx.y;
  const int qs = (by & 16) ? (15 - bx) : bx;  // long+short pair per CU
  const int bh = by;
  const int qw0 = qs * 128 + w * 32;
  const int hb = bh & 15, bb = bh >> 4;
  const int sw = lrow & 7;
  const f32x4 z4 = {0.f, 0.f, 0.f, 0.f};
  const s16x8 ones8 = {0x3F80, 0x3F80, 0x3F80, 0x3F80,
                       0x3F80, 0x3F80, 0x3F80, 0x3F80};  // bf16 1.0

  const u16* kbase = kg + ((long)bh << 11) * 64;
  const u16* vbase = vtg + ((long)bh << 6) * 2048;

  const int srow = lane >> 3;
  const int sxor8 = ((lane & 7) ^ srow) << 3;

  // Q fragments (pre-scaled by 1/8*log2e); used as MFMA B-operand
  s16x8 aq[2][2];
#pragma unroll
  for (int m = 0; m < 2; ++m)
#pragma unroll
    for (int kk = 0; kk < 2; ++kk)
      aq[m][kk] = *(const s16x8*)&qg[((bh << 11) + qw0 + m * 16 + lrow) * 64 +
                                     kk * 32 + lkg * 8];

  f32x4 o[2][4];   // O^T: lane holds O[q=qw0+16m+lrow][d=16d4+4lkg+r]
  f32x4 os[2];     // denominator carried in accumulator (all r identical)
  float mst[2];
#pragma unroll
  for (int m = 0; m < 2; ++m) {
#pragma unroll
    for (int d = 0; d < 4; ++d) o[m][d] = z4;
    os[m] = z4;
    mst[m] = -3e38f;
  }

  const int nt = 2 * qs + 2;

#define STAGE(BUF, TT)                                                         \
  {                                                                            \
    const int kv0s = (TT) << 6;                                                \
    _Pragma("unroll") for (int i = 0; i < 2; ++i) {                            \
      const int rr = ((i * 4 + w) << 3) + srow;                                \
      const int dst = (((i * 4 + w) << 6) + lane) << 3;                        \
      GLOAD_LDS16(kbase + ((kv0s + rr) << 6) + sxor8, &Ks[BUF][dst]);          \
      GLOAD_LDS16(vbase + ((long)rr << 11) + kv0s + sxor8, &Vs[BUF][dst]);     \
    }                                                                          \
  }

  STAGE(0, 0);
  int buf = 0;
  for (int tt = 0; tt < nt; ++tt) {
    const int kv0 = tt << 6;
    if (tt + 1 < nt) {
      STAGE(buf ^ 1, tt + 1);
      asm volatile("s_waitcnt vmcnt(4)" ::: "memory");
    } else {
      asm volatile("s_waitcnt vmcnt(0)" ::: "memory");
    }
    __builtin_amdgcn_s_barrier();
    __builtin_amdgcn_sched_barrier(0);

    if (kv0 < qw0 + 32) {
      // ---- S^T = K Q^T : s[m][c][r] = S[q=qw0+16m+lrow][kv=kv0+16c+4lkg+r] ----
      f32x4 s[2][4];
      __builtin_amdgcn_s_setprio(1);
#pragma unroll
      for (int c = 0; c < 4; ++c) {
        const int krow = c * 16 + lrow;
        s16x8 bk0 = *(const s16x8*)&Ks[buf][krow * 64 + ((lkg ^ sw) << 3)];
        s16x8 bk1 = *(const s16x8*)&Ks[buf][krow * 64 + (((4 + lkg) ^ sw) << 3)];
#pragma unroll
        for (int m = 0; m < 2; ++m)
          s[m][c] = mfma16(bk1, aq[m][1], mfma16(bk0, aq[m][0], z4));
      }
      __builtin_amdgcn_s_setprio(0);

      if (kv0 + 64 > qw0) {  // tile touches the diagonal: causal mask
#pragma unroll
        for (int m = 0; m < 2; ++m) {
          const int qrow = qw0 + m * 16 + lrow;
#pragma unroll
          for (int c = 0; c < 4; ++c) {
            const int kvb = kv0 + c * 16 + lkg * 4;
#pragma unroll
            for (int r = 0; r < 4; ++r)
              if (kvb + r > qrow) s[m][c][r] = -3e38f;
          }
        }
      }

      // ---- online softmax: lane-local row, shfl max-combine, pack P ----
      u16* PW = Ps[w];
#pragma unroll
      for (int m = 0; m < 2; ++m) {
        float lm = s[m][0][0];
#pragma unroll
        for (int c = 0; c < 4; ++c)
#pragma unroll
          for (int r = 0; r < 4; ++r) lm = fmaxf(lm, s[m][c][r]);
        lm = fmaxf(lm, __shfl_xor(lm, 16));
        lm = fmaxf(lm, __shfl_xor(lm, 32));
        const float mn = fmaxf(mst[m], lm);
        const float alm = exp2f(mst[m] - mn);
        mst[m] = mn;
#pragma unroll
        for (int d = 0; d < 4; ++d) o[m][d] *= alm;
        os[m] *= alm;
#pragma unroll
        for (int c = 0; c < 4; ++c) {
          const float p0 = exp2f(s[m][c][0] - mn);
          const float p1 = exp2f(s[m][c][1] - mn);
          const float p2 = exp2f(s[m][c][2] - mn);
          const float p3 = exp2f(s[m][c][3] - mn);
          const s16x4 pk4 =
              __builtin_bit_cast(s16x4, (u32x2){pk2bf(p0, p1), pk2bf(p2, p3)});
          *(s16x4*)&PW[(m * 16 + lrow) * 72 + c * 16 + lkg * 4] = pk4;
        }
      }

      // ---- B-fragments of P: contiguous b128 reads ----
      s16x8 pb[2][2];
#pragma unroll
      for (int m = 0; m < 2; ++m)
#pragma unroll
        for (int kk = 0; kk < 2; ++kk)
          pb[m][kk] =
              *(const s16x8*)&PW[(m * 16 + lrow) * 72 + kk * 32 + lkg * 8];

      // ---- O^T += V^T P^T ; denominator via ones-row MFMA ----
      __builtin_amdgcn_s_setprio(1);
#pragma unroll
      for (int d = 0; d < 4; ++d) {
        const int vrow = d * 16 + lrow;
        s16x8 bv0 = *(const s16x8*)&Vs[buf][vrow * 64 + ((lkg ^ sw) << 3)];
        s16x8 bv1 = *(const s16x8*)&Vs[buf][vrow * 64 + (((4 + lkg) ^ sw) << 3)];
#pragma unroll
        for (int m = 0; m < 2; ++m)
          o[m][d] = mfma16(bv1, pb[m][1], mfma16(bv0, pb[m][0], o[m][d]));
      }
#pragma unroll
      for (int m = 0; m < 2; ++m)
        os[m] = mfma16(ones8, pb[m][1], mfma16(ones8, pb[m][0], os[m]));
      __builtin_amdgcn_s_setprio(0);
    }

    __builtin_amdgcn_s_barrier();
    buf ^= 1;
  }

  // ---- normalize + store: 4-contig d per (m,d4) -> 8B stores ----
#pragma unroll
  for (int m = 0; m < 2; ++m) {
    const float inv = 1.0f / os[m][0];
    const int q = qw0 + m * 16 + lrow;
    u16* yrow = yb + ((long)((bb << 11) + q)) * 1024 + hb * 64;
#pragma unroll
    for (int d = 0; d < 4; ++d) {
      const s16x4 pk4 = __builtin_bit_cast(
          s16x4, (u32x2){pk2bf(o[m][d][0] * inv, o[m][d][1] * inv),
                         pk2bf(o[m][d][2] * inv, o[m][d][3] * inv)});
      *(s16x4*)&yrow[d * 16 + lkg * 4] = pk4;
    }
  }
#undef STAGE
}

extern "C" void kernel_launch(void* const* d_in, const int* in_sizes, int n_in,
                              void* d_out, int out_size, void* d_ws,
                              size_t ws_size, hipStream_t stream) {
  const float* x = (const float*)d_in[0];
  const float* wa = (const float*)d_in[1];
  const float* wp = (const float*)d_in[2];
  float* out = (float*)d_out;
  u16* ws = (u16*)d_ws;

  u16* xb = ws;                 // [4096][1024]
  u16* wat = xb + 4194304;      // [3072][1024]
  u16* wpt = wat + 3145728;     // [1024][1024]
  u16* qg = wpt + 1048576;      // [32][2048][64]
  u16* kg = qg + 4194304;       // [32][2048][64]
  u16* vtg = kg + 4194304;      // [32][64][2048]
  u16* yb = vtg + 4194304;      // [4096][1024]

  k_cvt<<<2048, 256, 0, stream>>>(x, xb, 4194304);
  k_transpose_cvt<<<dim3(48, 16), 256, 0, stream>>>(wa, wat, 1024, 3072);
  k_transpose_cvt<<<dim3(16, 16), 256, 0, stream>>>(wp, wpt, 1024, 1024);
  k_gemm<0><<<dim3(24, 32), 256, 0, stream>>>(xb, wat, qg, kg, vtg, nullptr,
                                              4096, 3072, 1024);
  k_attn<<<dim3(16, 32), 256, 0, stream>>>(qg, kg, vtg, yb);
  k_gemm2<<<dim3(8, 64), 256, 0, stream>>>(yb, wpt, out, 4096, 1024, 1024);
}